// Round 21
// baseline (26.803 us; speedup 1.0000x reference)
//
#include <hip/hip_runtime.h>

#define NB 8
#define NP 16
#define NS 256
#define NN 4096
#define NBP (NB*NP)             // 128
#define NCHUNK 8
#define CHUNK (NN/NCHUNK)       // 512 n per block
#define NBLK (NBP*NCHUNK)       // 1024
#define EPSV 1e-6f

typedef _Float16 half8 __attribute__((ext_vector_type(8)));
typedef _Float16 half2t __attribute__((ext_vector_type(2)));
typedef float    f32x4 __attribute__((ext_vector_type(4)));

#define H0 ((_Float16)0.0f)
#define H1 ((_Float16)1.0f)

// ---------------- workspace layout (bytes) ----------------
// minw : float[NBP*NS*NCHUNK] @ 0          (1 MB)  layout [bp][s][chunk]
// part : float[NBLK]          @ 0x100000
// s2p  : float[NBP]           @ 0x101000
// pp   : float[NBP]           @ 0x101200

// d2(s,n) as K=13 f16 hi/lo-split inner product (exact-pass R11/R13-R18).
// A = points (rows = n), B = surface (cols = s); mfma_f32_16x16x32_f16.
// Inner loop processes TWO s-tiles per iteration so the phase-1 update
// fuses to v_min3_f32 (one op per element instead of two) — ~35% fewer
// VALU ops in the hot loop, which is VALU-issue-bound at 4 waves/SIMD.

__global__ __launch_bounds__(256, 4) void sqreg_main(
    const float* __restrict__ sp,     // (B,P,S,3)
    const float* __restrict__ pts,    // (B,N,3)
    const float* __restrict__ assign, // (B,N,P)
    float* __restrict__ minw,         // [bp][s][chunk]
    float* __restrict__ partials)     // NBLK
{
    // Staging (live through MFMA loop): lsa [256][16] f16 @0, lpb [512][16] @8192.
    // Overlay (live after loop): pm1t [4][128][18] f16 @0, pm2 f32[4][256] @18432.
    __shared__ __align__(16) char smem[24576];
    _Float16 (*lsa)[16] = (_Float16(*)[16])smem;
    _Float16 (*lpb)[16] = (_Float16(*)[16])(smem + 8192);
    _Float16 (*pm1t)[128][18] = (_Float16(*)[128][18])smem;
    float    (*pm2)[NS] = (float(*)[NS])(smem + 18432);
    __shared__ __align__(16) _Float16 zrow[16];   // zero row for lanes>=32
    __shared__ float psum[4];

    const int bid   = blockIdx.x;
    const int bp    = bid >> 3;
    const int chunk = bid & 7;
    const int p     = bp & 15;
    const int b     = bp >> 4;
    const int tid   = threadIdx.x;
    const int lane  = tid & 63;
    const int wave  = tid >> 6;
    const int l15   = lane & 15;
    const int lg    = lane >> 4;

    // ---- stage: f32 -> hi/lo f16 fragment rows (1 s + 2 n per thread) ----
    if (tid < 16) zrow[tid] = H0;
    {
        const float* s3 = sp + (size_t)(bp*NS)*3;
        float x = s3[tid*3+0], y = s3[tid*3+1], z = s3[tid*3+2];
        float a2 = x*x + y*y + z*z;
        _Float16 xh=(_Float16)x, yh=(_Float16)y, zh=(_Float16)z, ah=(_Float16)a2;
        _Float16 xl=(_Float16)(x-(float)xh), yl=(_Float16)(y-(float)yh);
        _Float16 zl=(_Float16)(z-(float)zh), al=(_Float16)(a2-(float)ah);
        half8 blo = {xh,xh,xl,yh,yh,yl,zh,zh};
        half8 bhi = {zl,ah,al,H1,H1,H0,H0,H0};
        *(half8*)&lsa[tid][0] = blo;
        *(half8*)&lsa[tid][8] = bhi;

        const float* q3 = pts + (size_t)(b*NN + chunk*CHUNK)*3;
#pragma unroll
        for (int k = 0; k < 2; ++k) {
            int i = tid + k*256;
            float bx = q3[i*3+0], by = q3[i*3+1], bz = q3[i*3+2];
            float tx = -2.0f*bx, ty = -2.0f*by, tz = -2.0f*bz;
            float b2 = bx*bx + by*by + bz*bz;
            _Float16 txh=(_Float16)tx, tyh=(_Float16)ty, tzh=(_Float16)tz, bh=(_Float16)b2;
            _Float16 txl=(_Float16)(tx-(float)txh), tyl=(_Float16)(ty-(float)tyh);
            _Float16 tzl=(_Float16)(tz-(float)tzh), bl=(_Float16)(b2-(float)bh);
            half8 alo = {txh,txl,txh,tyh,tyl,tyh,tzh,tzl};
            half8 ahi = {tzh,H1,H1,bh,bl,H0,H0,H0};
            *(half8*)&lpb[i][0] = alo;
            *(half8*)&lpb[i][8] = ahi;
        }
    }
    __syncthreads();

    // ---- A fragments (unconditional loads; lanes>=32 hit zrow) ----
    const char* aptr = (lane < 32) ? (const char*)&lpb[wave*128 + l15][(lane>>4)*8]
                                   : (const char*)zrow;
    const int   astr = (lane < 32) ? 512 : 0;     // 16 rows * 32 B
    half8 afrag[8];
#pragma unroll
    for (int j = 0; j < 8; ++j)
        afrag[j] = *(const half8*)(aptr + j*astr);

    f32x4 rp1[8];                      // phase-1: min over s, per n-tile rows
#pragma unroll
    for (int j = 0; j < 8; ++j) rp1[j] = (f32x4){INFINITY,INFINITY,INFINITY,INFINITY};
    float rp2[16];                     // phase-2: min over n, per s-tile (lane col)
#pragma unroll
    for (int st = 0; st < 16; ++st) rp2[st] = INFINITY;

    // ---- MFMA sweep: paired s-tiles (2 per iter), 8 n-tiles each ----
    const char* bptr = (lane < 32) ? (const char*)&lsa[l15][(lane>>4)*8]
                                   : (const char*)zrow;
    const int   bstr = (lane < 32) ? 512 : 0;
    half8 bfA = *(const half8*)bptr;
    half8 bfB = *(const half8*)(bptr + bstr);
#pragma unroll
    for (int st = 0; st < 16; st += 2) {
        half8 bfA2 = bfA, bfB2 = bfB;
        if (st < 14) {
            bfA2 = *(const half8*)(bptr + (st+2)*bstr);
            bfB2 = *(const half8*)(bptr + (st+3)*bstr);
        }

        float tminA = INFINITY, tminB = INFINITY;
#pragma unroll
        for (int j = 0; j < 8; ++j) {
            f32x4 aA = __builtin_amdgcn_mfma_f32_16x16x32_f16(
                afrag[j], bfA, (f32x4){0.f,0.f,0.f,0.f}, 0, 0, 0);
            f32x4 aB = __builtin_amdgcn_mfma_f32_16x16x32_f16(
                afrag[j], bfB, (f32x4){0.f,0.f,0.f,0.f}, 0, 0, 0);
            // phase-1: one v_min3 per element (pairs the two s-tiles)
            rp1[j][0] = fminf(fminf(aA[0], aB[0]), rp1[j][0]);
            rp1[j][1] = fminf(fminf(aA[1], aB[1]), rp1[j][1]);
            rp1[j][2] = fminf(fminf(aA[2], aB[2]), rp1[j][2]);
            rp1[j][3] = fminf(fminf(aA[3], aB[3]), rp1[j][3]);
            // phase-2: per-s-tile running min (2 v_min3 each)
            tminA = fminf(fminf(aA[0], aA[1]), tminA);
            tminA = fminf(fminf(aA[2], aA[3]), tminA);
            tminB = fminf(fminf(aB[0], aB[1]), tminB);
            tminB = fminf(fminf(aB[2], aB[3]), tminB);
        }
        rp2[st]   = fminf(rp2[st],   tminA);
        rp2[st+1] = fminf(rp2[st+1], tminB);
        bfA = bfA2; bfB = bfB2;
    }

    __syncthreads();   // staging reads complete -> overlay becomes writable

    // ---- epilogue phase 2: fold rowgroups via shfl, store per-wave col mins ----
#pragma unroll
    for (int st = 0; st < 16; ++st) {
        float v = rp2[st];
        v = fminf(v, __shfl_xor(v, 16, 64));
        v = fminf(v, __shfl_xor(v, 32, 64));
        pm2[wave][st*16 + l15] = v;    // 4 lanes same addr/value: benign
    }

    // ---- epilogue phase 1: transpose col-partials (f16) into overlay LDS ----
#pragma unroll
    for (int j = 0; j < 8; ++j) {
#pragma unroll
        for (int r = 0; r < 4; ++r)
            pm1t[wave][j*16 + lg*4 + r][l15] = (_Float16)rp1[j][r];
    }
    __syncthreads();

    // ---- combine: minw (s = tid, transposed layout) + weighted phase-1 sum ----
    {
        float mm = fminf(fminf(pm2[0][tid], pm2[1][tid]),
                         fminf(pm2[2][tid], pm2[3][tid]));
        minw[(size_t)(bp*NS + tid)*NCHUNK + chunk] = fmaxf(mm, 0.0f);
    }
    float acc = 0.0f;
#pragma unroll
    for (int u = 0; u < 2; ++u) {
        int n = tid + u*256;
        const _Float16* row = pm1t[n >> 7][n & 127];
        float mm = INFINITY;
#pragma unroll
        for (int c = 0; c < 8; ++c) {
            half2t h = *(const half2t*)&row[2*c];   // ds_read_b32, 4B-aligned
            mm = fminf(mm, fminf((float)h.x, (float)h.y));
        }
        acc += fmaxf(mm, 0.0f) *
               assign[(size_t)(b*NN + chunk*CHUNK + n)*NP + p];
    }
#pragma unroll
    for (int msk = 32; msk >= 1; msk >>= 1)
        acc += __shfl_xor(acc, msk, 64);
    if (lane == 0) psum[wave] = acc;
    __syncthreads();
    if (tid == 0) partials[bid] = psum[0] + psum[1] + psum[2] + psum[3];
}

__global__ __launch_bounds__(256) void sqreg_tail(
    const float* __restrict__ minw,     // [bp][s][chunk]
    const float* __restrict__ partials, // NBLK
    float* __restrict__ s2p,            // NBP
    float* __restrict__ pp)             // NBP
{
    __shared__ float wsum[4];
    const int bp   = blockIdx.x;
    const int tid  = threadIdx.x;
    const int lane = tid & 63;
    const int wave = tid >> 6;

    // 8 chunk-values for s = tid are contiguous: two b128 loads
    const f32x4* base = (const f32x4*)(minw + (size_t)(bp*NS + tid)*NCHUNK);
    f32x4 v0 = base[0], v1 = base[1];
    float m = fminf(fminf(fminf(v0[0], v0[1]), fminf(v0[2], v0[3])),
                    fminf(fminf(v1[0], v1[1]), fminf(v1[2], v1[3])));
#pragma unroll
    for (int msk = 32; msk >= 1; msk >>= 1)
        m += __shfl_xor(m, msk, 64);
    if (lane == 0) wsum[wave] = m;
    __syncthreads();

    if (tid == 0) {
        s2p[bp] = (wsum[0] + wsum[1] + wsum[2] + wsum[3]) * (1.0f/(float)NS);
        float a = 0.0f;
#pragma unroll
        for (int c = 0; c < NCHUNK; ++c) a += partials[bp*NCHUNK + c];
        pp[bp] = a;
    }
}

__global__ __launch_bounds__(256) void sqreg_final(
    const float* __restrict__ s2p,
    const float* __restrict__ pp,
    const float* __restrict__ exist,   // (B,P)
    float* __restrict__ out)
{
    __shared__ float ppw[2];
    __shared__ float fin[8];
    const int tid = threadIdx.x;

    float tsum = (tid < NBP) ? pp[tid] : 0.0f;
#pragma unroll
    for (int msk = 32; msk >= 1; msk >>= 1)
        tsum += __shfl_xor(tsum, msk, 64);
    if (tid == 0)  ppw[0] = tsum;
    if (tid == 64) ppw[1] = tsum;

    if (tid < NBP) {                   // group of 16 lanes = one b
        float e  = exist[tid];
        float sv = s2p[tid] * e;
#pragma unroll
        for (int msk = 8; msk >= 1; msk >>= 1) {
            e  += __shfl_xor(e,  msk, 64);
            sv += __shfl_xor(sv, msk, 64);
        }
        if ((tid & 15) == 0) fin[tid >> 4] = sv / fmaxf(e, EPSV);
    }
    __syncthreads();

    if (tid == 0) {
        float sq = 0.0f;
#pragma unroll
        for (int g = 0; g < NB; ++g) sq += fin[g];
        out[0] = (ppw[0] + ppw[1]) / (float)(NB*NN) + sq * (1.0f/(float)NB);
    }
}

extern "C" void kernel_launch(void* const* d_in, const int* in_sizes, int n_in,
                              void* d_out, int out_size, void* d_ws, size_t ws_size,
                              hipStream_t stream) {
    const float* sp     = (const float*)d_in[0];
    const float* pts    = (const float*)d_in[1];
    const float* assign = (const float*)d_in[2];
    const float* exist  = (const float*)d_in[3];
    float* out = (float*)d_out;

    char* ws = (char*)d_ws;
    float* minw = (float*)(ws);
    float* part = (float*)(ws + 0x100000);
    float* s2p  = (float*)(ws + 0x101000);
    float* pp   = (float*)(ws + 0x101200);

    sqreg_main <<<NBLK, 256, 0, stream>>>(sp, pts, assign, minw, part);
    sqreg_tail <<<NBP,  256, 0, stream>>>(minw, part, s2p, pp);
    sqreg_final<<<1,    256, 0, stream>>>(s2p, pp, exist, out);
}

// Round 22
// 23.778 us; speedup vs baseline: 1.1272x; 1.1272x over previous
//
#include <hip/hip_runtime.h>

#define NB 8
#define NP 16
#define NS 256
#define NN 4096
#define NBP (NB*NP)             // 128
#define NCHUNK 8
#define CHUNK (NN/NCHUNK)       // 512 n per block
#define NBLK (NBP*NCHUNK)       // 1024
#define EPSV 1e-6f

typedef _Float16 half8 __attribute__((ext_vector_type(8)));
typedef _Float16 half2t __attribute__((ext_vector_type(2)));
typedef float    f32x4 __attribute__((ext_vector_type(4)));

#define H0 ((_Float16)0.0f)
#define H1 ((_Float16)1.0f)

// ---------------- workspace layout (bytes) ----------------
// minw : float[NBP*NS*NCHUNK] @ 0          (1 MB)  layout [bp][s][chunk]
// part : float[NBLK]          @ 0x100000
// s2p  : float[NBP]           @ 0x101000
// pp   : float[NBP]           @ 0x101200

// d2(s,n) as K=13 f16 hi/lo-split inner product (exact-pass R11/R13-R18).
// A = points (rows = n), B = surface (cols = s); mfma_f32_16x16x32_f16.
// Fragment loads are UNCONDITIONAL: lanes>=32 read a zeroed 32B row via a
// cndmask'd address (no exec divergence -> loads hoist/pipeline freely).
// pm1t f16 + pm2 both overlay the dead staging bytes -> ~24.6 KB static LDS.
// launch_bounds stays (256,4) (R16: (256,5) forced a 145 B/thread spill).
// R21 note: 2-s-tile pairing for v_min3 REGRESSED (+2.7 us) — the loop is
// latency-bound, not VALU-issue-bound; keep the single-tile form.

__global__ __launch_bounds__(256, 4) void sqreg_main(
    const float* __restrict__ sp,     // (B,P,S,3)
    const float* __restrict__ pts,    // (B,N,3)
    const float* __restrict__ assign, // (B,N,P)
    float* __restrict__ minw,         // [bp][s][chunk]
    float* __restrict__ partials)     // NBLK
{
    // Staging (live through MFMA loop): lsa [256][16] f16 @0, lpb [512][16] @8192.
    // Overlay (live after loop): pm1t [4][128][18] f16 @0, pm2 f32[4][256] @18432.
    __shared__ __align__(16) char smem[24576];
    _Float16 (*lsa)[16] = (_Float16(*)[16])smem;
    _Float16 (*lpb)[16] = (_Float16(*)[16])(smem + 8192);
    _Float16 (*pm1t)[128][18] = (_Float16(*)[128][18])smem;
    float    (*pm2)[NS] = (float(*)[NS])(smem + 18432);
    __shared__ __align__(16) _Float16 zrow[16];   // zero row for lanes>=32
    __shared__ float psum[4];

    const int bid   = blockIdx.x;
    const int bp    = bid >> 3;
    const int chunk = bid & 7;
    const int p     = bp & 15;
    const int b     = bp >> 4;
    const int tid   = threadIdx.x;
    const int lane  = tid & 63;
    const int wave  = tid >> 6;
    const int l15   = lane & 15;
    const int lg    = lane >> 4;

    // ---- stage: f32 -> hi/lo f16 fragment rows (1 s + 2 n per thread) ----
    if (tid < 16) zrow[tid] = H0;
    {
        const float* s3 = sp + (size_t)(bp*NS)*3;
        float x = s3[tid*3+0], y = s3[tid*3+1], z = s3[tid*3+2];
        float a2 = x*x + y*y + z*z;
        _Float16 xh=(_Float16)x, yh=(_Float16)y, zh=(_Float16)z, ah=(_Float16)a2;
        _Float16 xl=(_Float16)(x-(float)xh), yl=(_Float16)(y-(float)yh);
        _Float16 zl=(_Float16)(z-(float)zh), al=(_Float16)(a2-(float)ah);
        half8 blo = {xh,xh,xl,yh,yh,yl,zh,zh};
        half8 bhi = {zl,ah,al,H1,H1,H0,H0,H0};
        *(half8*)&lsa[tid][0] = blo;
        *(half8*)&lsa[tid][8] = bhi;

        const float* q3 = pts + (size_t)(b*NN + chunk*CHUNK)*3;
#pragma unroll
        for (int k = 0; k < 2; ++k) {
            int i = tid + k*256;
            float bx = q3[i*3+0], by = q3[i*3+1], bz = q3[i*3+2];
            float tx = -2.0f*bx, ty = -2.0f*by, tz = -2.0f*bz;
            float b2 = bx*bx + by*by + bz*bz;
            _Float16 txh=(_Float16)tx, tyh=(_Float16)ty, tzh=(_Float16)tz, bh=(_Float16)b2;
            _Float16 txl=(_Float16)(tx-(float)txh), tyl=(_Float16)(ty-(float)tyh);
            _Float16 tzl=(_Float16)(tz-(float)tzh), bl=(_Float16)(b2-(float)bh);
            half8 alo = {txh,txl,txh,tyh,tyl,tyh,tzh,tzl};
            half8 ahi = {tzh,H1,H1,bh,bl,H0,H0,H0};
            *(half8*)&lpb[i][0] = alo;
            *(half8*)&lpb[i][8] = ahi;
        }
    }
    __syncthreads();

    // ---- A fragments (unconditional loads; lanes>=32 hit zrow) ----
    const char* aptr = (lane < 32) ? (const char*)&lpb[wave*128 + l15][(lane>>4)*8]
                                   : (const char*)zrow;
    const int   astr = (lane < 32) ? 512 : 0;     // 16 rows * 32 B, or stay on zrow
    half8 afrag[8];
#pragma unroll
    for (int j = 0; j < 8; ++j)
        afrag[j] = *(const half8*)(aptr + j*astr);

    f32x4 rp1[8];                      // phase-1: min over s, per n-tile rows
#pragma unroll
    for (int j = 0; j < 8; ++j) rp1[j] = (f32x4){INFINITY,INFINITY,INFINITY,INFINITY};
    float rp2[16];                     // phase-2: min over n, per s-tile (lane col)
#pragma unroll
    for (int st = 0; st < 16; ++st) rp2[st] = INFINITY;

    // ---- MFMA sweep: 16 s-tiles x 8 n-tiles; bf prefetched one tile ahead ----
    const char* bptr = (lane < 32) ? (const char*)&lsa[l15][(lane>>4)*8]
                                   : (const char*)zrow;
    const int   bstr = (lane < 32) ? 512 : 0;
    half8 bf = *(const half8*)bptr;
#pragma unroll
    for (int st = 0; st < 16; ++st) {
        half8 bfn = bf;
        if (st < 15) bfn = *(const half8*)(bptr + (st+1)*bstr);

        float tmin = INFINITY;
#pragma unroll
        for (int j = 0; j < 8; ++j) {
            f32x4 acc = __builtin_amdgcn_mfma_f32_16x16x32_f16(
                afrag[j], bf, (f32x4){0.f,0.f,0.f,0.f}, 0, 0, 0);
            rp1[j][0] = fminf(rp1[j][0], acc[0]);
            rp1[j][1] = fminf(rp1[j][1], acc[1]);
            rp1[j][2] = fminf(rp1[j][2], acc[2]);
            rp1[j][3] = fminf(rp1[j][3], acc[3]);
            tmin = fminf(tmin, fminf(fminf(acc[0], acc[1]), fminf(acc[2], acc[3])));
        }
        rp2[st] = fminf(rp2[st], tmin);
        bf = bfn;
    }

    __syncthreads();   // staging reads complete -> overlay becomes writable

    // ---- epilogue phase 2: fold rowgroups via shfl, store per-wave col mins ----
#pragma unroll
    for (int st = 0; st < 16; ++st) {
        float v = rp2[st];
        v = fminf(v, __shfl_xor(v, 16, 64));
        v = fminf(v, __shfl_xor(v, 32, 64));
        pm2[wave][st*16 + l15] = v;    // 4 lanes same addr/value: benign
    }

    // ---- epilogue phase 1: transpose col-partials (f16) into overlay LDS ----
#pragma unroll
    for (int j = 0; j < 8; ++j) {
#pragma unroll
        for (int r = 0; r < 4; ++r)
            pm1t[wave][j*16 + lg*4 + r][l15] = (_Float16)rp1[j][r];
    }
    __syncthreads();

    // ---- combine: minw (s = tid, transposed layout) + weighted phase-1 sum ----
    {
        float mm = fminf(fminf(pm2[0][tid], pm2[1][tid]),
                         fminf(pm2[2][tid], pm2[3][tid]));
        minw[(size_t)(bp*NS + tid)*NCHUNK + chunk] = fmaxf(mm, 0.0f);
    }
    float acc = 0.0f;
#pragma unroll
    for (int u = 0; u < 2; ++u) {
        int n = tid + u*256;
        const _Float16* row = pm1t[n >> 7][n & 127];
        float mm = INFINITY;
#pragma unroll
        for (int c = 0; c < 8; ++c) {
            half2t h = *(const half2t*)&row[2*c];   // ds_read_b32, 4B-aligned
            mm = fminf(mm, fminf((float)h.x, (float)h.y));
        }
        acc += fmaxf(mm, 0.0f) *
               assign[(size_t)(b*NN + chunk*CHUNK + n)*NP + p];
    }
#pragma unroll
    for (int msk = 32; msk >= 1; msk >>= 1)
        acc += __shfl_xor(acc, msk, 64);
    if (lane == 0) psum[wave] = acc;
    __syncthreads();
    if (tid == 0) partials[bid] = psum[0] + psum[1] + psum[2] + psum[3];
}

__global__ __launch_bounds__(256) void sqreg_tail(
    const float* __restrict__ minw,     // [bp][s][chunk]
    const float* __restrict__ partials, // NBLK
    float* __restrict__ s2p,            // NBP
    float* __restrict__ pp)             // NBP
{
    __shared__ float wsum[4];
    const int bp   = blockIdx.x;
    const int tid  = threadIdx.x;
    const int lane = tid & 63;
    const int wave = tid >> 6;

    // 8 chunk-values for s = tid are contiguous: two b128 loads
    const f32x4* base = (const f32x4*)(minw + (size_t)(bp*NS + tid)*NCHUNK);
    f32x4 v0 = base[0], v1 = base[1];
    float m = fminf(fminf(fminf(v0[0], v0[1]), fminf(v0[2], v0[3])),
                    fminf(fminf(v1[0], v1[1]), fminf(v1[2], v1[3])));
#pragma unroll
    for (int msk = 32; msk >= 1; msk >>= 1)
        m += __shfl_xor(m, msk, 64);
    if (lane == 0) wsum[wave] = m;
    __syncthreads();

    if (tid == 0) {
        s2p[bp] = (wsum[0] + wsum[1] + wsum[2] + wsum[3]) * (1.0f/(float)NS);
        float a = 0.0f;
#pragma unroll
        for (int c = 0; c < NCHUNK; ++c) a += partials[bp*NCHUNK + c];
        pp[bp] = a;
    }
}

__global__ __launch_bounds__(256) void sqreg_final(
    const float* __restrict__ s2p,
    const float* __restrict__ pp,
    const float* __restrict__ exist,   // (B,P)
    float* __restrict__ out)
{
    __shared__ float ppw[2];
    __shared__ float fin[8];
    const int tid = threadIdx.x;

    float tsum = (tid < NBP) ? pp[tid] : 0.0f;
#pragma unroll
    for (int msk = 32; msk >= 1; msk >>= 1)
        tsum += __shfl_xor(tsum, msk, 64);
    if (tid == 0)  ppw[0] = tsum;
    if (tid == 64) ppw[1] = tsum;

    if (tid < NBP) {                   // group of 16 lanes = one b
        float e  = exist[tid];
        float sv = s2p[tid] * e;
#pragma unroll
        for (int msk = 8; msk >= 1; msk >>= 1) {
            e  += __shfl_xor(e,  msk, 64);
            sv += __shfl_xor(sv, msk, 64);
        }
        if ((tid & 15) == 0) fin[tid >> 4] = sv / fmaxf(e, EPSV);
    }
    __syncthreads();

    if (tid == 0) {
        float sq = 0.0f;
#pragma unroll
        for (int g = 0; g < NB; ++g) sq += fin[g];
        out[0] = (ppw[0] + ppw[1]) / (float)(NB*NN) + sq * (1.0f/(float)NB);
    }
}

extern "C" void kernel_launch(void* const* d_in, const int* in_sizes, int n_in,
                              void* d_out, int out_size, void* d_ws, size_t ws_size,
                              hipStream_t stream) {
    const float* sp     = (const float*)d_in[0];
    const float* pts    = (const float*)d_in[1];
    const float* assign = (const float*)d_in[2];
    const float* exist  = (const float*)d_in[3];
    float* out = (float*)d_out;

    char* ws = (char*)d_ws;
    float* minw = (float*)(ws);
    float* part = (float*)(ws + 0x100000);
    float* s2p  = (float*)(ws + 0x101000);
    float* pp   = (float*)(ws + 0x101200);

    sqreg_main <<<NBLK, 256, 0, stream>>>(sp, pts, assign, minw, part);
    sqreg_tail <<<NBP,  256, 0, stream>>>(minw, part, s2p, pp);
    sqreg_final<<<1,    256, 0, stream>>>(s2p, pp, exist, out);
}